// Round 1
// baseline (24229.700 us; speedup 1.0000x reference)
//
#include <hip/hip_runtime.h>
#include <hip/hip_bf16.h>
#include <math.h>

#define B_   128
#define S_   1024
#define I_   512
#define H_   1024
#define NG   4096   // 4*H
#define KC   1536   // I + H

typedef __bf16 v8bf __attribute__((ext_vector_type(8)));
typedef float  v4f  __attribute__((ext_vector_type(4)));

__device__ inline v8bf cvt8(const float4 a, const float4 b) {
    v8bf r;
    r[0] = (__bf16)a.x; r[1] = (__bf16)a.y; r[2] = (__bf16)a.z; r[3] = (__bf16)a.w;
    r[4] = (__bf16)b.x; r[5] = (__bf16)b.y; r[6] = (__bf16)b.z; r[7] = (__bf16)b.w;
    return r;
}

// One-time per-call setup: pack W_ih||W_hh -> bf16 [4096][1536], bias = b_ih+b_hh,
// zero h (both buffers) and c state.
__global__ void lstm_setup(const float* __restrict__ Wih, const float* __restrict__ Whh,
                           const float* __restrict__ bih, const float* __restrict__ bhh,
                           __bf16* __restrict__ Wc, float* __restrict__ bias,
                           __bf16* __restrict__ hA, __bf16* __restrict__ hB,
                           float* __restrict__ cbuf)
{
    const size_t NT = (size_t)NG * KC;
    for (size_t i = (size_t)blockIdx.x * 256 + threadIdx.x; i < NT;
         i += (size_t)gridDim.x * 256) {
        const int n = (int)(i / KC);
        const int k = (int)(i % KC);
        const float v = (k < I_) ? Wih[(size_t)n * I_ + k]
                                 : Whh[(size_t)n * H_ + (k - I_)];
        Wc[i] = (__bf16)v;
        if (i < NG) bias[i] = bih[i] + bhh[i];
        if (i < (size_t)B_ * H_) {
            hA[i] = (__bf16)0.f;
            hB[i] = (__bf16)0.f;
            cbuf[i] = 0.f;
        }
    }
}

// One LSTM timestep. Grid: (64, 4) WGs; block: 256 threads = 4 waves.
// WG computes h-tile [32 batch rows x 16 h cols]; wave w computes gate w's
// [32 x 16] slice of the gate pre-activations via MFMA over K=1536, then the
// WG exchanges gates through LDS and does the c/h update.
__global__ __launch_bounds__(256) void lstm_step(
    const float* __restrict__ seq, const int* __restrict__ len,
    const __bf16* __restrict__ Wc, const float* __restrict__ bias,
    const __bf16* __restrict__ hrd, __bf16* __restrict__ hwr,
    float* __restrict__ cbuf, float* __restrict__ out, int t)
{
    __shared__ float g_lds[4][32][16];

    const int tid  = threadIdx.x;
    const int wave = tid >> 6;
    const int lane = tid & 63;
    const int l15  = lane & 15;
    const int lk   = (lane >> 4) * 8;

    const int hcol0 = blockIdx.x * 16;   // [0,1024) step 16
    const int brow0 = blockIdx.y * 32;   // {0,32,64,96}
    const int n0    = wave * H_ + hcol0; // gate-col base for this wave

    v4f acc0 = {0.f, 0.f, 0.f, 0.f};
    v4f acc1 = {0.f, 0.f, 0.f, 0.f};

    // B operand: Wc is [N=4096][K=1536] row-major (i.e. W^T layout).
    // Lane holds col = n0 + (lane&15), k = lk + j.
    const __bf16* wrow = Wc + (size_t)(n0 + l15) * KC + lk;

    // A operand rows (batch rows) for the two 16-row M blocks.
    const int arow0 = brow0 + l15;
    const float*  xr0 = seq + (size_t)arow0 * (S_ * I_) + (size_t)t * I_ + lk;
    const float*  xr1 = xr0 + (size_t)16 * (S_ * I_);
    const __bf16* hr0 = hrd + (size_t)arow0 * H_ + lk;
    const __bf16* hr1 = hr0 + 16 * H_;

    // K region 1: x part (k in [0,512)), fp32 -> bf16 on the fly.
    #pragma unroll 4
    for (int kc = 0; kc < I_; kc += 32) {
        const float4* p0 = (const float4*)(xr0 + kc);
        const float4* p1 = (const float4*)(xr1 + kc);
        v8bf a0 = cvt8(p0[0], p0[1]);
        v8bf a1 = cvt8(p1[0], p1[1]);
        v8bf b  = *(const v8bf*)(wrow + kc);
        acc0 = __builtin_amdgcn_mfma_f32_16x16x32_bf16(a0, b, acc0, 0, 0, 0);
        acc1 = __builtin_amdgcn_mfma_f32_16x16x32_bf16(a1, b, acc1, 0, 0, 0);
    }
    // K region 2: h part (k in [512,1536)), bf16 state.
    #pragma unroll 4
    for (int kc = 0; kc < H_; kc += 32) {
        v8bf a0 = *(const v8bf*)(hr0 + kc);
        v8bf a1 = *(const v8bf*)(hr1 + kc);
        v8bf b  = *(const v8bf*)(wrow + I_ + kc);
        acc0 = __builtin_amdgcn_mfma_f32_16x16x32_bf16(a0, b, acc0, 0, 0, 0);
        acc1 = __builtin_amdgcn_mfma_f32_16x16x32_bf16(a1, b, acc1, 0, 0, 0);
    }

    // Bias (depends on gate col only; D col = lane&15).
    const float bval = bias[n0 + l15];
    const int dr = (lane >> 4) * 4;
    #pragma unroll
    for (int r = 0; r < 4; ++r) {
        g_lds[wave][dr + r][l15]      = acc0[r] + bval;
        g_lds[wave][16 + dr + r][l15] = acc1[r] + bval;
    }
    __syncthreads();

    // Elementwise LSTM update: 512 (b,h) cells, 2 per thread.
    #pragma unroll
    for (int idx = tid; idx < 512; idx += 256) {
        const int lr = idx >> 4;
        const int lc = idx & 15;
        const int b  = brow0 + lr;
        const size_t off = (size_t)b * H_ + (hcol0 + lc);

        const float ig = g_lds[0][lr][lc];
        const float fg = g_lds[1][lr][lc];
        const float gg = g_lds[2][lr][lc];
        const float og = g_lds[3][lr][lc];

        const float c_old = cbuf[off];
        const float si = 1.f / (1.f + __expf(-ig));
        const float sf = 1.f / (1.f + __expf(-fg));
        const float so = 1.f / (1.f + __expf(-og));
        const float cn = sf * c_old + si * tanhf(gg);
        const float hv = so * tanhf(cn);

        cbuf[off] = cn;
        hwr[off]  = (__bf16)hv;
        if (t == len[b] - 1) out[off] = hv;
    }
}

extern "C" void kernel_launch(void* const* d_in, const int* in_sizes, int n_in,
                              void* d_out, int out_size, void* d_ws, size_t ws_size,
                              hipStream_t stream) {
    const float* seq = (const float*)d_in[0];
    const int*   len = (const int*)d_in[1];
    const float* Wih = (const float*)d_in[2];
    const float* Whh = (const float*)d_in[3];
    const float* bih = (const float*)d_in[4];
    const float* bhh = (const float*)d_in[5];
    float* out = (float*)d_out;

    char* ws = (char*)d_ws;
    // Workspace layout (assumes ws_size >= ~13.7 MB):
    //   Wc   bf16 [4096][1536]  : 12,582,912 B
    //   bias f32  [4096]        :     16,384 B
    //   hA   bf16 [128][1024]   :    262,144 B
    //   hB   bf16 [128][1024]   :    262,144 B
    //   c    f32  [128][1024]   :    524,288 B
    __bf16* Wc   = (__bf16*)(ws);
    float*  bias = (float*)(ws + 12582912);
    __bf16* hA   = (__bf16*)(ws + 12599296);
    __bf16* hB   = (__bf16*)(ws + 12861440);
    float*  cbuf = (float*)(ws + 13123584);

    lstm_setup<<<dim3(4096), dim3(256), 0, stream>>>(Wih, Whh, bih, bhh,
                                                     Wc, bias, hA, hB, cbuf);

    for (int t = 0; t < S_; ++t) {
        const __bf16* hrd = (t & 1) ? hB : hA;
        __bf16*       hwr = (t & 1) ? hA : hB;
        lstm_step<<<dim3(64, 4), dim3(256), 0, stream>>>(seq, len, Wc, bias,
                                                         hrd, hwr, cbuf, out, t);
    }
}

// Round 2
// 19794.469 us; speedup vs baseline: 1.2241x; 1.2241x over previous
//
#include <hip/hip_runtime.h>
#include <hip/hip_bf16.h>
#include <math.h>

#define B_   128
#define S_   1024
#define I_   512
#define H_   1024
#define NWG  256
#define NTHR 512
#define LDA  1544   // LDS A-panel row stride in elements (1536 + 8 pad -> 2-way-free b128)

typedef __bf16 v8bf __attribute__((ext_vector_type(8)));
typedef float  v4f  __attribute__((ext_vector_type(4)));

__device__ __forceinline__ v8bf cvt8(const float4 a, const float4 b) {
    v8bf r;
    r[0] = (__bf16)a.x; r[1] = (__bf16)a.y; r[2] = (__bf16)a.z; r[3] = (__bf16)a.w;
    r[4] = (__bf16)b.x; r[5] = (__bf16)b.y; r[6] = (__bf16)b.z; r[7] = (__bf16)b.w;
    return r;
}

__device__ __forceinline__ float sigm(float x) { return 1.f / (1.f + __expf(-x)); }
__device__ __forceinline__ float tanh_fast(float x) {
    const float xc = fminf(fmaxf(x, -15.f), 15.f);
    const float e  = __expf(2.f * xc);
    return (e - 1.f) / (e + 1.f);
}

// Two-level grid barrier. bar layout (uints): [g*16] 8 group counters (64 B apart),
// [128] root counter, [192] release epoch. Zeroed via hipMemsetAsync each call.
// Epochs are absolute (1..S_), thresholds derived from epoch -> no reuse hazard.
__device__ __forceinline__ void grid_barrier(unsigned* bar, int wg, unsigned epoch) {
    __syncthreads();
    if (threadIdx.x == 0) {
        __threadfence();  // device-scope release: drain + write back local L2
        const int g = wg & 7;
        unsigned old = __hip_atomic_fetch_add(&bar[g * 16], 1u, __ATOMIC_ACQ_REL,
                                              __HIP_MEMORY_SCOPE_AGENT);
        if (old == epoch * 32u - 1u) {  // last of my 32-WG group
            unsigned ro = __hip_atomic_fetch_add(&bar[128], 1u, __ATOMIC_ACQ_REL,
                                                 __HIP_MEMORY_SCOPE_AGENT);
            if (ro == epoch * 8u - 1u) {  // last group overall
                __hip_atomic_store(&bar[192], epoch, __ATOMIC_RELEASE,
                                   __HIP_MEMORY_SCOPE_AGENT);
            }
        }
        while (__hip_atomic_load(&bar[192], __ATOMIC_RELAXED,
                                 __HIP_MEMORY_SCOPE_AGENT) < epoch) {
            __builtin_amdgcn_s_sleep(2);
        }
        __threadfence();  // device-scope acquire: invalidate stale L2 lines
    }
    __syncthreads();
}

__global__ __launch_bounds__(NTHR, 2) void lstm_persist(
    const float* __restrict__ seq, const int* __restrict__ len,
    const float* __restrict__ Wih, const float* __restrict__ Whh,
    const float* __restrict__ bih, const float* __restrict__ bhh,
    float* __restrict__ out, __bf16* __restrict__ hA, __bf16* __restrict__ hB,
    unsigned* __restrict__ bar)
{
    __shared__ __bf16 Apan[16 * LDA];        // [batch 16][x 512 | h 1024] bf16
    __shared__ float  glds[4][2][16][33];    // [gate][k-half][batch][hcol(+pad)]

    const int wg   = blockIdx.x;
    const int bg   = wg >> 5;    // batch group [0,8): rows bg*16+[0,16)
    const int cg   = wg & 31;    // h-col group [0,32): cols cg*32+[0,32)
    const int tid  = threadIdx.x;
    const int lane = tid & 63;
    const int wv   = tid >> 6;
    const int l15  = lane & 15;
    const int q    = lane >> 4;  // [0,4)
    const int gate = wv >> 1;    // [0,4): i,f,g,o
    const int ks   = wv & 1;     // k-half: k in [ks*768, ks*768+768)

    // This wave's two 16-col B tiles (gate columns of Wc = [Wih | Whh]):
    const int n0   = gate * H_ + cg * 32;
    const int col0 = n0 + l15;
    const int col1 = n0 + 16 + l15;

    // ---- one-time: weights (fp32 -> bf16) into registers: 2 x 24 k-tiles ----
    v8bf w0[24], w1[24];
    #pragma unroll
    for (int j = 0; j < 24; ++j) {
        const int kt = ks * 24 + j;          // global k-tile [0,48)
        const int k  = kt * 32 + q * 8;
        if (kt < 16) {                        // x region (k < 512)
            const float4* p0 = (const float4*)&Wih[(size_t)col0 * I_ + k];
            const float4* p1 = (const float4*)&Wih[(size_t)col1 * I_ + k];
            w0[j] = cvt8(p0[0], p0[1]);
            w1[j] = cvt8(p1[0], p1[1]);
        } else {                              // h region
            const float4* p0 = (const float4*)&Whh[(size_t)col0 * H_ + (k - I_)];
            const float4* p1 = (const float4*)&Whh[(size_t)col1 * H_ + (k - I_)];
            w0[j] = cvt8(p0[0], p0[1]);
            w1[j] = cvt8(p1[0], p1[1]);
        }
    }
    const float b0 = ks ? 0.f : (bih[col0] + bhh[col0]);
    const float b1 = ks ? 0.f : (bih[col1] + bhh[col1]);

    // ---- per-thread cell: (local batch cb, local h-col cc) ----
    const int cb = tid >> 5;                 // [0,16)
    const int cc = tid & 31;                 // [0,32)
    const int gb = bg * 16 + cb;             // global batch row
    const int gc = cg * 32 + cc;             // global h col
    const int mylen = len[gb];
    float creg = 0.f;

    for (int t = 0; t < S_; ++t) {
        const __bf16* hrd = (t & 1) ? hB : hA;
        __bf16*       hwr = (t & 1) ? hA : hB;

        // ---- stage x_t (cvt to bf16) and h_prev into LDS panel ----
        {
            const float4* xp = (const float4*)&seq[((size_t)gb * S_ + (size_t)t) * I_ + cc * 16];
            v8bf* dx = (v8bf*)&Apan[cb * LDA + cc * 16];
            const float4 x0 = xp[0], x1 = xp[1];
            dx[0] = cvt8(x0, x1);
            const float4 x2 = xp[2], x3 = xp[3];
            dx[1] = cvt8(x2, x3);

            const v8bf* hp = (const v8bf*)&hrd[(size_t)gb * H_ + cc * 32];
            v8bf* dh = (v8bf*)&Apan[cb * LDA + I_ + cc * 32];
            const v8bf h0 = hp[0], h1 = hp[1];
            dh[0] = h0; dh[1] = h1;
            const v8bf h2 = hp[2], h3 = hp[3];
            dh[2] = h2; dh[3] = h3;
        }
        __syncthreads();

        // ---- MFMA: 24 k-tiles, A-frag shared across the wave's 2 N-tiles ----
        v4f acc0 = {0.f, 0.f, 0.f, 0.f};
        v4f acc1 = {0.f, 0.f, 0.f, 0.f};
        const __bf16* ap = &Apan[l15 * LDA + ks * 768 + q * 8];
        #pragma unroll
        for (int j = 0; j < 24; ++j) {
            const v8bf a = *(const v8bf*)(ap + j * 32);
            acc0 = __builtin_amdgcn_mfma_f32_16x16x32_bf16(a, w0[j], acc0, 0, 0, 0);
            acc1 = __builtin_amdgcn_mfma_f32_16x16x32_bf16(a, w1[j], acc1, 0, 0, 0);
        }

        // ---- exchange gate pre-activations (D: row=q*4+r batch, col=l15) ----
        #pragma unroll
        for (int r = 0; r < 4; ++r) {
            glds[gate][ks][q * 4 + r][l15]      = acc0[r] + b0;
            glds[gate][ks][q * 4 + r][16 + l15] = acc1[r] + b1;
        }
        __syncthreads();

        // ---- cell update (c in register) ----
        const float ig = glds[0][0][cb][cc] + glds[0][1][cb][cc];
        const float fg = glds[1][0][cb][cc] + glds[1][1][cb][cc];
        const float gg = glds[2][0][cb][cc] + glds[2][1][cb][cc];
        const float og = glds[3][0][cb][cc] + glds[3][1][cb][cc];

        const float cn = sigm(fg) * creg + sigm(ig) * tanh_fast(gg);
        const float hv = sigm(og) * tanh_fast(cn);
        creg = cn;

        hwr[(size_t)gb * H_ + gc] = (__bf16)hv;
        if (t == mylen - 1) out[(size_t)gb * H_ + gc] = hv;

        // ---- grid-wide barrier (publishes h_next device-wide) ----
        grid_barrier(bar, wg, (unsigned)(t + 1));
    }
}

extern "C" void kernel_launch(void* const* d_in, const int* in_sizes, int n_in,
                              void* d_out, int out_size, void* d_ws, size_t ws_size,
                              hipStream_t stream) {
    const float* seq = (const float*)d_in[0];
    const int*   len = (const int*)d_in[1];
    const float* Wih = (const float*)d_in[2];
    const float* Whh = (const float*)d_in[3];
    const float* bih = (const float*)d_in[4];
    const float* bhh = (const float*)d_in[5];
    float* out = (float*)d_out;

    char* ws = (char*)d_ws;
    unsigned* bar = (unsigned*)ws;                       // 1 KB barrier state
    __bf16* hA   = (__bf16*)(ws + 4096);                 // 256 KB
    __bf16* hB   = (__bf16*)(ws + 4096 + 262144);        // 256 KB

    hipMemsetAsync(bar, 0, 1024, stream);                // reset barrier epochs
    hipMemsetAsync(hA, 0, (size_t)B_ * H_ * 2, stream);  // h(-1) = 0

    void* args[] = {(void*)&seq, (void*)&len, (void*)&Wih, (void*)&Whh,
                    (void*)&bih, (void*)&bhh, (void*)&out, (void*)&hA,
                    (void*)&hB, (void*)&bar};
    hipError_t e = hipLaunchCooperativeKernel((void*)lstm_persist, dim3(NWG),
                                              dim3(NTHR), args, 0, stream);
    if (e != hipSuccess) {
        // Fallback: plain launch (grid == 1 WG/CU fits co-resident anyway).
        lstm_persist<<<dim3(NWG), dim3(NTHR), 0, stream>>>(seq, len, Wih, Whh,
                                                           bih, bhh, out, hA, hB, bar);
    }
}

// Round 3
// 3598.272 us; speedup vs baseline: 6.7337x; 5.5011x over previous
//
#include <hip/hip_runtime.h>
#include <hip/hip_bf16.h>
#include <math.h>

#define B_   128
#define S_   1024
#define I_   512
#define H_   1024
#define NWG  256
#define NTHR 512
#define LDA  1544   // LDS A-panel row stride (1536 + 8 pad)

typedef __bf16 v8bf __attribute__((ext_vector_type(8)));
typedef float  v4f  __attribute__((ext_vector_type(4)));

__device__ __forceinline__ v8bf cvt8(const float4 a, const float4 b) {
    v8bf r;
    r[0] = (__bf16)a.x; r[1] = (__bf16)a.y; r[2] = (__bf16)a.z; r[3] = (__bf16)a.w;
    r[4] = (__bf16)b.x; r[5] = (__bf16)b.y; r[6] = (__bf16)b.z; r[7] = (__bf16)b.w;
    return r;
}

__device__ __forceinline__ float sigm(float x) { return 1.f / (1.f + __expf(-x)); }
__device__ __forceinline__ float tanh_fast(float x) {
    const float xc = fminf(fmaxf(x, -15.f), 15.f);
    const float e  = __expf(2.f * xc);
    return (e - 1.f) / (e + 1.f);
}

// Persistent LSTM. 256 WGs = 8 batch-groups x 32 col-groups. Batch-groups are
// fully independent; within a group, h is exchanged via relaxed agent-scope
// atomics (coherent, no L2 writeback/invalidate) + a per-(bg,t) arrival counter.
__global__ __launch_bounds__(NTHR, 1) void lstm_persist(
    const float* __restrict__ seq, const int* __restrict__ len,
    const float* __restrict__ Wih, const float* __restrict__ Whh,
    const float* __restrict__ bih, const float* __restrict__ bhh,
    float* __restrict__ out, __bf16* __restrict__ hA, __bf16* __restrict__ hB,
    unsigned* __restrict__ cnt)
{
    __shared__ __bf16 Apan[16 * LDA];        // [batch 16][x 512 | h 1024] bf16
    __shared__ float  glds[4][2][16][33];    // [gate][k-half][batch][hcol(+pad)]

    const int wg   = blockIdx.x;
    const int bg   = wg >> 5;    // batch group [0,8): rows bg*16+[0,16)
    const int cg   = wg & 31;    // h-col group [0,32): cols cg*32+[0,32)
    const int tid  = threadIdx.x;
    const int lane = tid & 63;
    const int wv   = tid >> 6;
    const int l15  = lane & 15;
    const int q    = lane >> 4;  // [0,4)
    const int gate = wv >> 1;    // [0,4): i,f,g,o
    const int ks   = wv & 1;     // k-half: k in [ks*768, ks*768+768)

    const int n0   = gate * H_ + cg * 32;
    const int col0 = n0 + l15;
    const int col1 = n0 + 16 + l15;

    // ---- one-time: weights (fp32 -> bf16) into registers: 2 x 24 k-tiles ----
    v8bf w0[24], w1[24];
    #pragma unroll
    for (int j = 0; j < 24; ++j) {
        const int kt = ks * 24 + j;          // global k-tile [0,48)
        const int k  = kt * 32 + q * 8;
        if (kt < 16) {                        // x region (k < 512)
            const float4* p0 = (const float4*)&Wih[(size_t)col0 * I_ + k];
            const float4* p1 = (const float4*)&Wih[(size_t)col1 * I_ + k];
            w0[j] = cvt8(p0[0], p0[1]);
            w1[j] = cvt8(p1[0], p1[1]);
        } else {                              // h region
            const float4* p0 = (const float4*)&Whh[(size_t)col0 * H_ + (k - I_)];
            const float4* p1 = (const float4*)&Whh[(size_t)col1 * H_ + (k - I_)];
            w0[j] = cvt8(p0[0], p0[1]);
            w1[j] = cvt8(p1[0], p1[1]);
        }
    }
    const float b0 = ks ? 0.f : (bih[col0] + bhh[col0]);
    const float b1 = ks ? 0.f : (bih[col1] + bhh[col1]);

    // ---- per-thread cell: (local batch cb, local h-col cc), 1 cell/thread ----
    const int cb = tid >> 5;                 // [0,16)
    const int cc = tid & 31;                 // [0,32)
    const int gb = bg * 16 + cb;             // global batch row
    const int gc = cg * 32 + cc;             // global h col
    const int mylen = len[gb];
    float creg = 0.f;

    unsigned* mycnt = cnt + (size_t)bg * S_; // per-(bg, t) arrival counters

    for (int t = 0; t < S_; ++t) {
        // h_t lives in buf[t&1]; h_{-1} (zeros) in hB.
        const __bf16* hrd = (t & 1) ? hA : hB;
        __bf16*       hwr = (t & 1) ? hB : hA;

        // ---- stage x_t (cvt to bf16) into LDS; loads overlap the poll ----
        {
            const float4* xp = (const float4*)&seq[((size_t)gb * S_ + (size_t)t) * I_ + cc * 16];
            v8bf* dx = (v8bf*)&Apan[cb * LDA + cc * 16];
            const float4 x0 = xp[0], x1 = xp[1];
            dx[0] = cvt8(x0, x1);
            const float4 x2 = xp[2], x3 = xp[3];
            dx[1] = cvt8(x2, x3);
        }

        // ---- wait until all 32 WGs of this batch group published h_{t-1} ----
        if (t > 0 && tid == 0) {
            while (__hip_atomic_load(&mycnt[t - 1], __ATOMIC_RELAXED,
                                     __HIP_MEMORY_SCOPE_AGENT) < 32u) {
                __builtin_amdgcn_s_sleep(1);
            }
        }
        __syncthreads();
        asm volatile("" ::: "memory");

        // ---- stage h_{t-1} via relaxed agent atomic 8B loads (coherent) ----
        {
            const unsigned long long* hs =
                (const unsigned long long*)(hrd + (size_t)(bg * 16) * H_);
            // row cb has 256 ull; thread reads 8 at cc + 32*j (coalesced-ish)
            unsigned long long vals[8];
            #pragma unroll
            for (int j = 0; j < 8; ++j)
                vals[j] = __hip_atomic_load(&hs[cb * 256 + cc + 32 * j],
                                            __ATOMIC_RELAXED, __HIP_MEMORY_SCOPE_AGENT);
            #pragma unroll
            for (int j = 0; j < 8; ++j)
                *(unsigned long long*)&Apan[cb * LDA + I_ + 4 * (cc + 32 * j)] = vals[j];
        }
        __syncthreads();

        // ---- MFMA: 24 k-tiles, A-frag shared across the wave's 2 N-tiles ----
        v4f acc0 = {0.f, 0.f, 0.f, 0.f};
        v4f acc1 = {0.f, 0.f, 0.f, 0.f};
        const __bf16* ap = &Apan[l15 * LDA + ks * 768 + q * 8];
        #pragma unroll
        for (int j = 0; j < 24; ++j) {
            const v8bf a = *(const v8bf*)(ap + j * 32);
            acc0 = __builtin_amdgcn_mfma_f32_16x16x32_bf16(a, w0[j], acc0, 0, 0, 0);
            acc1 = __builtin_amdgcn_mfma_f32_16x16x32_bf16(a, w1[j], acc1, 0, 0, 0);
        }

        // ---- exchange gate pre-activations (D: row=q*4+r batch, col=l15) ----
        #pragma unroll
        for (int r = 0; r < 4; ++r) {
            glds[gate][ks][q * 4 + r][l15]      = acc0[r] + b0;
            glds[gate][ks][q * 4 + r][16 + l15] = acc1[r] + b1;
        }
        __syncthreads();

        // ---- cell update (c in register) ----
        const float ig = glds[0][0][cb][cc] + glds[0][1][cb][cc];
        const float fg = glds[1][0][cb][cc] + glds[1][1][cb][cc];
        const float gg = glds[2][0][cb][cc] + glds[2][1][cb][cc];
        const float og = glds[3][0][cb][cc] + glds[3][1][cb][cc];

        const float cn = sigm(fg) * creg + sigm(ig) * tanh_fast(gg);
        const float hv = sigm(og) * tanh_fast(cn);
        creg = cn;

        // ---- publish h_t: pack 2 bf16 per lane-pair, relaxed agent store ----
        const __bf16 hb = (__bf16)hv;
        const unsigned short us = __builtin_bit_cast(unsigned short, hb);
        const unsigned nb = __shfl_xor((unsigned)us, 1);
        if ((lane & 1) == 0) {
            const unsigned pair = (unsigned)us | (nb << 16);
            __hip_atomic_store((unsigned*)&hwr[(size_t)gb * H_ + gc], pair,
                               __ATOMIC_RELAXED, __HIP_MEMORY_SCOPE_AGENT);
        }
        if (t == mylen - 1) out[(size_t)gb * H_ + gc] = hv;

        // ---- signal arrival (stores drained by syncthreads' vmcnt(0)) ----
        __syncthreads();
        if (tid == 0) {
            __hip_atomic_fetch_add(&mycnt[t], 1u, __ATOMIC_RELAXED,
                                   __HIP_MEMORY_SCOPE_AGENT);
        }
    }
}

extern "C" void kernel_launch(void* const* d_in, const int* in_sizes, int n_in,
                              void* d_out, int out_size, void* d_ws, size_t ws_size,
                              hipStream_t stream) {
    const float* seq = (const float*)d_in[0];
    const int*   len = (const int*)d_in[1];
    const float* Wih = (const float*)d_in[2];
    const float* Whh = (const float*)d_in[3];
    const float* bih = (const float*)d_in[4];
    const float* bhh = (const float*)d_in[5];
    float* out = (float*)d_out;

    char* ws = (char*)d_ws;
    unsigned* cnt = (unsigned*)ws;                       // 8*1024*4 = 32 KB
    __bf16* hA   = (__bf16*)(ws + 32768);                // 256 KB
    __bf16* hB   = (__bf16*)(ws + 32768 + 262144);       // 256 KB

    hipMemsetAsync(cnt, 0, 8 * S_ * sizeof(unsigned), stream);
    hipMemsetAsync(hA, 0, (size_t)B_ * H_ * 2 * sizeof(__bf16), stream);  // hA+hB

    void* args[] = {(void*)&seq, (void*)&len, (void*)&Wih, (void*)&Whh,
                    (void*)&bih, (void*)&bhh, (void*)&out, (void*)&hA,
                    (void*)&hB, (void*)&cnt};
    hipError_t e = hipLaunchCooperativeKernel((void*)lstm_persist, dim3(NWG),
                                              dim3(NTHR), args, 0, stream);
    if (e != hipSuccess) {
        // Fallback: plain launch; 256 WGs over 256 CUs are co-resident.
        lstm_persist<<<dim3(NWG), dim3(NTHR), 0, stream>>>(seq, len, Wih, Whh,
                                                           bih, bhh, out, hA, hB, cnt);
    }
}

// Round 4
// 3352.288 us; speedup vs baseline: 7.2278x; 1.0734x over previous
//
#include <hip/hip_runtime.h>
#include <hip/hip_bf16.h>
#include <math.h>

#define B_   128
#define S_   1024
#define I_   512
#define H_   1024
#define KC   1536
#define NWG  256
#define NTHR 512
#define LDA  1544   // LDS A-panel row stride (1536 + 8 pad)

typedef __bf16 v8bf __attribute__((ext_vector_type(8)));
typedef float  v4f  __attribute__((ext_vector_type(4)));

__device__ __forceinline__ v8bf cvt8(const float4 a, const float4 b) {
    v8bf r;
    r[0] = (__bf16)a.x; r[1] = (__bf16)a.y; r[2] = (__bf16)a.z; r[3] = (__bf16)a.w;
    r[4] = (__bf16)b.x; r[5] = (__bf16)b.y; r[6] = (__bf16)b.z; r[7] = (__bf16)b.w;
    return r;
}

__device__ __forceinline__ float sigm(float x) { return 1.f / (1.f + __expf(-x)); }
__device__ __forceinline__ float tanh_fast(float x) {
    const float xc = fminf(fmaxf(x, -15.f), 15.f);
    const float e  = __expf(2.f * xc);
    return (e - 1.f) / (e + 1.f);
}

// Pack W_ih||W_hh (fp32) -> Wc bf16 [4096][1536] row-major. 8 elems/thread.
__global__ void lstm_pack(const float* __restrict__ Wih, const float* __restrict__ Whh,
                          __bf16* __restrict__ Wc)
{
    const size_t e = ((size_t)blockIdx.x * 256 + threadIdx.x) * 8;  // 8 | 1536
    const int col = (int)(e / KC);
    const int k   = (int)(e % KC);
    const float4* src = (k < I_) ? (const float4*)&Wih[(size_t)col * I_ + k]
                                 : (const float4*)&Whh[(size_t)col * H_ + (k - I_)];
    const float4 a = src[0], b = src[1];
    *(v8bf*)&Wc[e] = cvt8(a, b);
}

// Persistent LSTM. 256 WGs; bg = wg&7 (XCD-local batch groups of 32 WGs),
// cg = wg>>3. Wave (gate,ks): x k in [ks*256,+256), h k in [512+ks*512,+512).
__global__ __launch_bounds__(NTHR, 2) void lstm_persist(
    const float* __restrict__ seq, const int* __restrict__ len,
    const __bf16* __restrict__ Wc,
    const float* __restrict__ bih, const float* __restrict__ bhh,
    float* __restrict__ out, __bf16* __restrict__ hA, __bf16* __restrict__ hB,
    unsigned* __restrict__ cnt)
{
    __shared__ __bf16 Apan[16 * LDA];        // [batch 16][x 512 | h 1024]
    __shared__ float  glds[4][2][16][33];    // [gate][k-half][batch][hcol+pad]

    const int wg   = blockIdx.x;
    const int bg   = wg & 7;     // batch group: rows bg*16+[0,16)  (XCD-local)
    const int cg   = wg >> 3;    // h-col group: cols cg*32+[0,32)
    const int tid  = threadIdx.x;
    const int lane = tid & 63;
    const int wv   = tid >> 6;
    const int l15  = lane & 15;
    const int q    = lane >> 4;
    const int gate = wv >> 1;
    const int ks   = wv & 1;

    const int n0   = gate * H_ + cg * 32;
    const int col0 = n0 + l15;
    const int col1 = n0 + 16 + l15;

    // ---- one-time: bf16 weights into registers (pinned) ----
    v8bf wx0[8], wx1[8], wh0[16], wh1[16];
    {
        const __bf16* wr0 = Wc + (size_t)col0 * KC;
        const __bf16* wr1 = Wc + (size_t)col1 * KC;
        const int xo = ks * 256 + q * 8;
        const int ho = I_ + ks * 512 + q * 8;
        #pragma unroll
        for (int j = 0; j < 8; ++j) {
            wx0[j] = *(const v8bf*)(wr0 + xo + j * 32);
            wx1[j] = *(const v8bf*)(wr1 + xo + j * 32);
        }
        #pragma unroll
        for (int j = 0; j < 16; ++j) {
            wh0[j] = *(const v8bf*)(wr0 + ho + j * 32);
            wh1[j] = *(const v8bf*)(wr1 + ho + j * 32);
        }
        #pragma unroll
        for (int j = 0; j < 8; ++j)
            asm volatile("" : "+v"(wx0[j]), "+v"(wx1[j]));
        #pragma unroll
        for (int j = 0; j < 16; ++j)
            asm volatile("" : "+v"(wh0[j]), "+v"(wh1[j]));
    }
    const float b0 = ks ? 0.f : (bih[col0] + bhh[col0]);
    const float b1 = ks ? 0.f : (bih[col1] + bhh[col1]);

    // ---- per-thread cell ----
    const int cb = tid >> 5;                 // [0,16)
    const int cc = tid & 31;                 // [0,32)
    const int gb = bg * 16 + cb;
    const int gc = cg * 32 + cc;
    const int mylen = len[gb];
    float creg = 0.f;

    for (int t = 0; t < S_; ++t) {
        const __bf16* hrd = (t & 1) ? hA : hB;   // h_{t-1}
        __bf16*       hwr = (t & 1) ? hB : hA;   // h_t

        // ---- stage x_t into LDS (overlaps the poll below) ----
        {
            const float4* xp = (const float4*)&seq[((size_t)gb * S_ + (size_t)t) * I_ + cc * 16];
            v8bf* dx = (v8bf*)&Apan[cb * LDA + cc * 16];
            const float4 x0 = xp[0], x1 = xp[1];
            dx[0] = cvt8(x0, x1);
            const float4 x2 = xp[2], x3 = xp[3];
            dx[1] = cvt8(x2, x3);
        }

        // ---- wait for h_{t-1} from all 32 WGs of this batch group ----
        if (t > 0 && tid == 0) {
            const unsigned* c0 = cnt + ((size_t)(t - 1) * 4) * 32 + bg;
            unsigned s;
            do {
                s  = __hip_atomic_load(c0 +  0, __ATOMIC_RELAXED, __HIP_MEMORY_SCOPE_AGENT);
                s += __hip_atomic_load(c0 + 32, __ATOMIC_RELAXED, __HIP_MEMORY_SCOPE_AGENT);
                s += __hip_atomic_load(c0 + 64, __ATOMIC_RELAXED, __HIP_MEMORY_SCOPE_AGENT);
                s += __hip_atomic_load(c0 + 96, __ATOMIC_RELAXED, __HIP_MEMORY_SCOPE_AGENT);
            } while (s < 32u);
        }
        __syncthreads();  // b1: x staged, h_{t-1} published

        // ---- issue h loads (coherent 8B atomics), hide under x-MFMA ----
        unsigned long long hv8[8];
        {
            const unsigned long long* hs =
                (const unsigned long long*)(hrd + (size_t)(bg * 16) * H_);
            #pragma unroll
            for (int j = 0; j < 8; ++j)
                hv8[j] = __hip_atomic_load(&hs[cb * 256 + cc + 32 * j],
                                           __ATOMIC_RELAXED, __HIP_MEMORY_SCOPE_AGENT);
        }

        // ---- x-part MFMA (independent of h) ----
        v4f acc0 = {0.f, 0.f, 0.f, 0.f};
        v4f acc1 = {0.f, 0.f, 0.f, 0.f};
        {
            const __bf16* ap = &Apan[l15 * LDA + ks * 256 + q * 8];
            #pragma unroll
            for (int j = 0; j < 8; ++j) {
                const v8bf a = *(const v8bf*)(ap + j * 32);
                acc0 = __builtin_amdgcn_mfma_f32_16x16x32_bf16(a, wx0[j], acc0, 0, 0, 0);
                acc1 = __builtin_amdgcn_mfma_f32_16x16x32_bf16(a, wx1[j], acc1, 0, 0, 0);
            }
        }

        // ---- land h into LDS ----
        #pragma unroll
        for (int j = 0; j < 8; ++j)
            *(unsigned long long*)&Apan[cb * LDA + I_ + 4 * (cc + 32 * j)] = hv8[j];
        __syncthreads();  // b2: h panel ready

        // ---- h-part MFMA ----
        {
            const __bf16* ap = &Apan[l15 * LDA + I_ + ks * 512 + q * 8];
            #pragma unroll
            for (int j = 0; j < 16; ++j) {
                const v8bf a = *(const v8bf*)(ap + j * 32);
                acc0 = __builtin_amdgcn_mfma_f32_16x16x32_bf16(a, wh0[j], acc0, 0, 0, 0);
                acc1 = __builtin_amdgcn_mfma_f32_16x16x32_bf16(a, wh1[j], acc1, 0, 0, 0);
            }
        }

        // ---- exchange gate pre-activations ----
        #pragma unroll
        for (int r = 0; r < 4; ++r) {
            glds[gate][ks][q * 4 + r][l15]      = acc0[r] + b0;
            glds[gate][ks][q * 4 + r][16 + l15] = acc1[r] + b1;
        }
        __syncthreads();  // b3

        // ---- cell update ----
        const float ig = glds[0][0][cb][cc] + glds[0][1][cb][cc];
        const float fg = glds[1][0][cb][cc] + glds[1][1][cb][cc];
        const float gg = glds[2][0][cb][cc] + glds[2][1][cb][cc];
        const float og = glds[3][0][cb][cc] + glds[3][1][cb][cc];

        const float cn = sigm(fg) * creg + sigm(ig) * tanh_fast(gg);
        const float hv = sigm(og) * tanh_fast(cn);
        creg = cn;

        // ---- publish h_t (packed 4B relaxed agent stores) ----
        const __bf16 hb = (__bf16)hv;
        const unsigned short us = __builtin_bit_cast(unsigned short, hb);
        const unsigned nb = __shfl_xor((unsigned)us, 1);
        if ((lane & 1) == 0) {
            const unsigned pair = (unsigned)us | (nb << 16);
            __hip_atomic_store((unsigned*)&hwr[(size_t)gb * H_ + gc], pair,
                               __ATOMIC_RELAXED, __HIP_MEMORY_SCOPE_AGENT);
        }
        if (t == mylen - 1) out[(size_t)gb * H_ + gc] = hv;

        __syncthreads();  // b4: drains h stores (vmcnt 0 before barrier)
        if (tid == 0)
            __hip_atomic_fetch_add(cnt + ((size_t)t * 4 + (cg & 3)) * 32 + bg, 1u,
                                   __ATOMIC_RELAXED, __HIP_MEMORY_SCOPE_AGENT);
    }
}

extern "C" void kernel_launch(void* const* d_in, const int* in_sizes, int n_in,
                              void* d_out, int out_size, void* d_ws, size_t ws_size,
                              hipStream_t stream) {
    const float* seq = (const float*)d_in[0];
    const int*   len = (const int*)d_in[1];
    const float* Wih = (const float*)d_in[2];
    const float* Whh = (const float*)d_in[3];
    const float* bih = (const float*)d_in[4];
    const float* bhh = (const float*)d_in[5];
    float* out = (float*)d_out;

    char* ws = (char*)d_ws;
    __bf16*   Wc  = (__bf16*)ws;                          // 12,582,912 B
    __bf16*   hA  = (__bf16*)(ws + 12582912);             //    262,144 B
    __bf16*   hB  = (__bf16*)(ws + 12845056);             //    262,144 B
    unsigned* cnt = (unsigned*)(ws + 13107200);           //    524,288 B

    hipMemsetAsync(hA, 0, 2 * (size_t)B_ * H_ * sizeof(__bf16), stream);  // hA+hB
    hipMemsetAsync(cnt, 0, (size_t)S_ * 4 * 32 * sizeof(unsigned), stream);

    lstm_pack<<<dim3(3072), dim3(256), 0, stream>>>(Wih, Whh, Wc);

    void* args[] = {(void*)&seq, (void*)&len, (void*)&Wc, (void*)&bih,
                    (void*)&bhh, (void*)&out, (void*)&hA, (void*)&hB, (void*)&cnt};
    hipError_t e = hipLaunchCooperativeKernel((void*)lstm_persist, dim3(NWG),
                                              dim3(NTHR), args, 0, stream);
    if (e != hipSuccess) {
        lstm_persist<<<dim3(NWG), dim3(NTHR), 0, stream>>>(seq, len, Wc, bih,
                                                           bhh, out, hA, hB, cnt);
    }
}

// Round 6
// 3348.413 us; speedup vs baseline: 7.2362x; 1.0012x over previous
//
#include <hip/hip_runtime.h>
#include <hip/hip_bf16.h>
#include <math.h>

#define B_   128
#define S_   1024
#define I_   512
#define H_   1024
#define KC   1536
#define NWG  256
#define NTHR 512
#define LDA  1544   // LDS A-panel row stride (1536 + 8 pad)

typedef __bf16 v8bf __attribute__((ext_vector_type(8)));
typedef float  v4f  __attribute__((ext_vector_type(4)));

__device__ __forceinline__ v8bf cvt8(const float4 a, const float4 b) {
    v8bf r;
    r[0] = (__bf16)a.x; r[1] = (__bf16)a.y; r[2] = (__bf16)a.z; r[3] = (__bf16)a.w;
    r[4] = (__bf16)b.x; r[5] = (__bf16)b.y; r[6] = (__bf16)b.z; r[7] = (__bf16)b.w;
    return r;
}

__device__ __forceinline__ float sigm(float x) { return 1.f / (1.f + __expf(-x)); }
__device__ __forceinline__ float tanh_fast(float x) {
    const float xc = fminf(fmaxf(x, -15.f), 15.f);
    const float e  = __expf(2.f * xc);
    return (e - 1.f) / (e + 1.f);
}

// Pack W_ih||W_hh (fp32) -> Wc bf16 [4096][1536] row-major. 8 elems/thread.
__global__ void lstm_pack(const float* __restrict__ Wih, const float* __restrict__ Whh,
                          __bf16* __restrict__ Wc)
{
    const size_t e = ((size_t)blockIdx.x * 256 + threadIdx.x) * 8;  // 8 | 1536
    const int col = (int)(e / KC);
    const int k   = (int)(e % KC);
    const float4* src = (k < I_) ? (const float4*)&Wih[(size_t)col * I_ + k]
                                 : (const float4*)&Whh[(size_t)col * H_ + (k - I_)];
    const float4 a = src[0], b = src[1];
    *(v8bf*)&Wc[e] = cvt8(a, b);
}

// Persistent LSTM. 256 WGs = 1/CU; bg = wg&7 (XCD-local batch groups of 32 WGs),
// cg = wg>>3. Wave (gate,ks): x k in [ks*256,+256), h k in [512+ks*512,+512).
// __launch_bounds__(512,1): 512-reg/lane budget so the 192 weight VGPRs stay
// resident for the whole kernel (1 WG/CU is all we launch anyway).
__global__ __launch_bounds__(NTHR, 1) void lstm_persist(
    const float* __restrict__ seq, const int* __restrict__ len,
    const __bf16* __restrict__ Wc,
    const float* __restrict__ bih, const float* __restrict__ bhh,
    float* __restrict__ out, __bf16* __restrict__ hA, __bf16* __restrict__ hB,
    unsigned* __restrict__ cnt)
{
    __shared__ __bf16 Apan[16 * LDA];        // [batch 16][x 512 | h 1024]
    __shared__ float  glds[4][2][16][33];    // [gate][k-half][batch][hcol+pad]

    const int wg   = blockIdx.x;
    const int bg   = wg & 7;     // batch group: rows bg*16+[0,16)  (XCD-local)
    const int cg   = wg >> 3;    // h-col group: cols cg*32+[0,32)
    const int tid  = threadIdx.x;
    const int lane = tid & 63;
    const int wv   = tid >> 6;
    const int l15  = lane & 15;
    const int q    = lane >> 4;
    const int gate = wv >> 1;
    const int ks   = wv & 1;

    const int n0   = gate * H_ + cg * 32;
    const int col0 = n0 + l15;
    const int col1 = n0 + 16 + l15;

    // ---- one-time: bf16 weights into registers (pinned, resident) ----
    v8bf wx0[8], wx1[8], wh0[16], wh1[16];
    {
        const __bf16* wr0 = Wc + (size_t)col0 * KC;
        const __bf16* wr1 = Wc + (size_t)col1 * KC;
        const int xo = ks * 256 + q * 8;
        const int ho = I_ + ks * 512 + q * 8;
        #pragma unroll
        for (int j = 0; j < 8; ++j) {
            wx0[j] = *(const v8bf*)(wr0 + xo + j * 32);
            wx1[j] = *(const v8bf*)(wr1 + xo + j * 32);
        }
        #pragma unroll
        for (int j = 0; j < 16; ++j) {
            wh0[j] = *(const v8bf*)(wr0 + ho + j * 32);
            wh1[j] = *(const v8bf*)(wr1 + ho + j * 32);
        }
        #pragma unroll
        for (int j = 0; j < 8; ++j)
            asm volatile("" : "+v"(wx0[j]), "+v"(wx1[j]));
        #pragma unroll
        for (int j = 0; j < 16; ++j)
            asm volatile("" : "+v"(wh0[j]), "+v"(wh1[j]));
    }
    const float b0 = ks ? 0.f : (bih[col0] + bhh[col0]);
    const float b1 = ks ? 0.f : (bih[col1] + bhh[col1]);

    // ---- per-thread cell ----
    const int cb = tid >> 5;                 // [0,16)
    const int cc = tid & 31;                 // [0,32)
    const int gb = bg * 16 + cb;
    const int gc = cg * 32 + cc;
    const int mylen = len[gb];
    float creg = 0.f;

    for (int t = 0; t < S_; ++t) {
        const __bf16* hrd = (t & 1) ? hA : hB;   // h_{t-1}
        __bf16*       hwr = (t & 1) ? hB : hA;   // h_t

        // ---- stage x_t into LDS (overlaps the poll below) ----
        {
            const float4* xp = (const float4*)&seq[((size_t)gb * S_ + (size_t)t) * I_ + cc * 16];
            v8bf* dx = (v8bf*)&Apan[cb * LDA + cc * 16];
            const float4 x0 = xp[0], x1 = xp[1];
            dx[0] = cvt8(x0, x1);
            const float4 x2 = xp[2], x3 = xp[3];
            dx[1] = cvt8(x2, x3);
        }

        // ---- wait for h_{t-1} from all 32 WGs of this batch group ----
        if (t > 0 && tid == 0) {
            const unsigned* c0 = cnt + ((size_t)(t - 1) * 4) * 32 + bg;
            unsigned s;
            do {
                s  = __hip_atomic_load(c0 +  0, __ATOMIC_RELAXED, __HIP_MEMORY_SCOPE_AGENT);
                s += __hip_atomic_load(c0 + 32, __ATOMIC_RELAXED, __HIP_MEMORY_SCOPE_AGENT);
                s += __hip_atomic_load(c0 + 64, __ATOMIC_RELAXED, __HIP_MEMORY_SCOPE_AGENT);
                s += __hip_atomic_load(c0 + 96, __ATOMIC_RELAXED, __HIP_MEMORY_SCOPE_AGENT);
            } while (s < 32u);
        }
        __syncthreads();  // b1: x staged, h_{t-1} published

        // ---- issue h loads (coherent 8B atomics), hide under x-MFMA ----
        unsigned long long hv8[8];
        {
            const unsigned long long* hs =
                (const unsigned long long*)(hrd + (size_t)(bg * 16) * H_);
            #pragma unroll
            for (int j = 0; j < 8; ++j)
                hv8[j] = __hip_atomic_load(&hs[cb * 256 + cc + 32 * j],
                                           __ATOMIC_RELAXED, __HIP_MEMORY_SCOPE_AGENT);
        }

        // ---- x-part MFMA (independent of h) ----
        v4f acc0 = {0.f, 0.f, 0.f, 0.f};
        v4f acc1 = {0.f, 0.f, 0.f, 0.f};
        {
            const __bf16* ap = &Apan[l15 * LDA + ks * 256 + q * 8];
            #pragma unroll
            for (int j = 0; j < 8; ++j) {
                const v8bf a = *(const v8bf*)(ap + j * 32);
                acc0 = __builtin_amdgcn_mfma_f32_16x16x32_bf16(a, wx0[j], acc0, 0, 0, 0);
                acc1 = __builtin_amdgcn_mfma_f32_16x16x32_bf16(a, wx1[j], acc1, 0, 0, 0);
            }
        }

        // ---- land h into LDS ----
        #pragma unroll
        for (int j = 0; j < 8; ++j)
            *(unsigned long long*)&Apan[cb * LDA + I_ + 4 * (cc + 32 * j)] = hv8[j];
        __syncthreads();  // b2: h panel ready

        // ---- h-part MFMA ----
        {
            const __bf16* ap = &Apan[l15 * LDA + I_ + ks * 512 + q * 8];
            #pragma unroll
            for (int j = 0; j < 16; ++j) {
                const v8bf a = *(const v8bf*)(ap + j * 32);
                acc0 = __builtin_amdgcn_mfma_f32_16x16x32_bf16(a, wh0[j], acc0, 0, 0, 0);
                acc1 = __builtin_amdgcn_mfma_f32_16x16x32_bf16(a, wh1[j], acc1, 0, 0, 0);
            }
        }

        // ---- exchange gate pre-activations ----
        #pragma unroll
        for (int r = 0; r < 4; ++r) {
            glds[gate][ks][q * 4 + r][l15]      = acc0[r] + b0;
            glds[gate][ks][q * 4 + r][16 + l15] = acc1[r] + b1;
        }
        __syncthreads();  // b3

        // ---- cell update ----
        const float ig = glds[0][0][cb][cc] + glds[0][1][cb][cc];
        const float fg = glds[1][0][cb][cc] + glds[1][1][cb][cc];
        const float gg = glds[2][0][cb][cc] + glds[2][1][cb][cc];
        const float og = glds[3][0][cb][cc] + glds[3][1][cb][cc];

        const float cn = sigm(fg) * creg + sigm(ig) * tanh_fast(gg);
        const float hv = sigm(og) * tanh_fast(cn);
        creg = cn;

        // ---- publish h_t (packed 4B relaxed agent stores) ----
        const __bf16 hb = (__bf16)hv;
        const unsigned short us = __builtin_bit_cast(unsigned short, hb);
        const unsigned nb = __shfl_xor((unsigned)us, 1);
        if ((lane & 1) == 0) {
            const unsigned pair = (unsigned)us | (nb << 16);
            __hip_atomic_store((unsigned*)&hwr[(size_t)gb * H_ + gc], pair,
                               __ATOMIC_RELAXED, __HIP_MEMORY_SCOPE_AGENT);
        }
        if (t == mylen - 1) out[(size_t)gb * H_ + gc] = hv;

        __syncthreads();  // b4: drains h stores (vmcnt 0 before barrier)
        if (tid == 0)
            __hip_atomic_fetch_add(cnt + ((size_t)t * 4 + (cg & 3)) * 32 + bg, 1u,
                                   __ATOMIC_RELAXED, __HIP_MEMORY_SCOPE_AGENT);
    }
}

extern "C" void kernel_launch(void* const* d_in, const int* in_sizes, int n_in,
                              void* d_out, int out_size, void* d_ws, size_t ws_size,
                              hipStream_t stream) {
    const float* seq = (const float*)d_in[0];
    const int*   len = (const int*)d_in[1];
    const float* Wih = (const float*)d_in[2];
    const float* Whh = (const float*)d_in[3];
    const float* bih = (const float*)d_in[4];
    const float* bhh = (const float*)d_in[5];
    float* out = (float*)d_out;

    char* ws = (char*)d_ws;
    __bf16*   Wc  = (__bf16*)ws;                          // 12,582,912 B
    __bf16*   hA  = (__bf16*)(ws + 12582912);             //    262,144 B
    __bf16*   hB  = (__bf16*)(ws + 12845056);             //    262,144 B
    unsigned* cnt = (unsigned*)(ws + 13107200);           //    524,288 B

    hipMemsetAsync(hA, 0, 2 * (size_t)B_ * H_ * sizeof(__bf16), stream);  // hA+hB
    hipMemsetAsync(cnt, 0, (size_t)S_ * 4 * 32 * sizeof(unsigned), stream);

    lstm_pack<<<dim3(3072), dim3(256), 0, stream>>>(Wih, Whh, Wc);

    void* args[] = {(void*)&seq, (void*)&len, (void*)&Wc, (void*)&bih,
                    (void*)&bhh, (void*)&out, (void*)&hA, (void*)&hB, (void*)&cnt};
    hipError_t e = hipLaunchCooperativeKernel((void*)lstm_persist, dim3(NWG),
                                              dim3(NTHR), args, 0, stream);
    if (e != hipSuccess) {
        lstm_persist<<<dim3(NWG), dim3(NTHR), 0, stream>>>(seq, len, Wc, bih,
                                                           bhh, out, hA, hB, cnt);
    }
}